// Round 3
// baseline (1315.454 us; speedup 1.0000x reference)
//
#include <hip/hip_runtime.h>
#include <math.h>

#define BATCH 16
#define CDIM 256
#define NCLS 80
#define N3 16384
#define N4 4096
#define N5 1024
#define NTOK 21504
#define KQ 300
#define KSEL 512
#define CANDMAX 1024
#define TBLK 128
#define NBLK 168

typedef __attribute__((ext_vector_type(8))) short short8;
typedef __attribute__((ext_vector_type(16))) float floatx16;
typedef unsigned short ushort_t;

#define ZEROV {0.f,0.f,0.f,0.f,0.f,0.f,0.f,0.f,0.f,0.f,0.f,0.f,0.f,0.f,0.f,0.f}
// h1/h2 LDS address: [tok][col] bf16, 16B-chunk XOR-swizzled by (tok&7)
#define H1S(tok, col) (((tok) << 8) + (((((col) >> 3) ^ ((tok) & 7)) << 3) | ((col) & 7)))

__device__ __forceinline__ float sigmoidf_(float x) {
    return 1.0f / (1.0f + __expf(-x));
}

__device__ __forceinline__ ushort_t f2bf(float f) {   // RNE f32->bf16
    unsigned int x = __float_as_uint(f);
    unsigned int r = (x + 0x7FFFu + ((x >> 16) & 1u)) >> 16;
    return (ushort_t)r;
}

__device__ __forceinline__ void locate_level(
    int n, int bb,
    const float* __restrict__ s3, const float* __restrict__ s4, const float* __restrict__ s5,
    const float*& src, int& nloc, int& lsz)
{
    if (n < N3)           { src = s3 + (size_t)bb * CDIM * N3; nloc = n;           lsz = N3; }
    else if (n < N3 + N4) { src = s4 + (size_t)bb * CDIM * N4; nloc = n - N3;      lsz = N4; }
    else                  { src = s5 + (size_t)bb * CDIM * N5; nloc = n - N3 - N4; lsz = N5; }
}

// -------- Kernel 0: pack weights into 32x32x16-MFMA B-fragment order --------
// chunks 0..2: w_score (padded to 96 cols); 3..10: w1; 11..18: w2; block 19: w3
// (4 cols zero-padded to 32). Frag f, lane l: W^T[col=cb+(l&31)][k=16f+8*(l>>5)+j].
__global__ __launch_bounds__(256) void prep_weights(
    const float* __restrict__ w1, const float* __restrict__ w2,
    const float* __restrict__ w_score, const float* __restrict__ w3,
    ushort_t* __restrict__ wPk, ushort_t* __restrict__ w3Pk)
{
    const int c = blockIdx.x;          // 0..19
    for (int i = threadIdx.x; i < 8192; i += 256) {
        const int f = i >> 9;          // 0..15
        const int e = i & 511;
        const int lni = e >> 3;        // 0..63 (lane)
        const int j = e & 7;
        const int col = lni & 31;
        const int k = 16 * f + (lni >> 5) * 8 + j;
        float v;
        if (c < 3) {
            const int cc = 32 * c + col;
            v = (cc < NCLS) ? w_score[k * NCLS + cc] : 0.f;
        } else if (c < 11) {
            v = w1[k * 256 + (32 * (c - 3) + col)];
        } else if (c < 19) {
            v = w2[k * 256 + (32 * (c - 11) + col)];
        } else {
            v = (col < 4) ? w3[k * 4 + col] : 0.f;
        }
        ushort_t* dst = (c < 19) ? (wPk + (size_t)c * 8192) : w3Pk;
        dst[i] = f2bf(v);
    }
}

// -------- Kernel 1: fused encoder head, 32x32x16 bf16 MFMA, M=64/wave --------
// grid: BATCH*168 blocks of 128 tokens; 256 threads = 4 waves.
// wave w: token-group tw=w&1 (64 tokens = 2 tiles of 32), chunk parity cw=w>>1.
// A fragments load DIRECT from global (no LDS staging); B fragments load
// coalesced from packed weights (L1/L2-resident); each B frag feeds 2
// independent acc chains (tile 0/1). LDS only for the h1/h2 round-trip.
__global__ __launch_bounds__(256, 2) void enc_mfma_kernel(
    const float* __restrict__ s3, const float* __restrict__ s4, const float* __restrict__ s5,
    const ushort_t* __restrict__ wPk, const ushort_t* __restrict__ w3Pk,
    const float* __restrict__ b_score, const float* __restrict__ b1,
    const float* __restrict__ b2, const float* __restrict__ b3,
    float* __restrict__ out_logits, float* __restrict__ out_sboxes,
    float* __restrict__ ws_scores)
{
    __shared__ __align__(16) ushort_t h1b[TBLK * 256];   // 64 KB, swizzled
    __shared__ float smax_s[2][TBLK];                    // 1 KB

    const int t = threadIdx.x;
    const int lane = t & 63;
    const int w = t >> 6;
    const int tw = w & 1;
    const int cw = w >> 1;
    const int ln = lane & 31;
    const int half = lane >> 5;

    const int bb = blockIdx.x / NBLK;
    const int tile = blockIdx.x % NBLK;
    const int T0 = tile * TBLK;          // 128-token tiles never span a level

    const float* src; int nloc, lsz;
    locate_level(T0, bb, s3, s4, s5, src, nloc, lsz);

    // ---- A1 fragments direct from global: A[row=tok][k=16f+8*half+j] ----
    short8 af[2][16];
    #pragma unroll
    for (int tt = 0; tt < 2; ++tt) {
        const float* colp = src + (size_t)(nloc + 64 * tw + 32 * tt + ln);
        #pragma unroll
        for (int f = 0; f < 16; ++f) {
            const size_t kb = (size_t)(16 * f + 8 * half);
            float r[8];
            #pragma unroll
            for (int j = 0; j < 8; ++j) r[j] = colp[(kb + j) * (size_t)lsz];
            short8 a;
            #pragma unroll
            for (int j = 0; j < 8; ++j) a[j] = (short)f2bf(r[j]);
            af[tt][f] = a;
        }
    }

    const int gt00 = bb * NTOK + T0;

    // chunk compute: 16 B-frag loads, 32 MFMAs as 2 interleaved indep chains
    auto mm2 = [&](const ushort_t* bp, floatx16& a0, floatx16& a1) {
        short8 blo[8], bhi[8];
        #pragma unroll
        for (int f2 = 0; f2 < 8; ++f2)
            blo[f2] = *(const short8*)&bp[(size_t)f2 * 512 + lane * 8];
        #pragma unroll
        for (int f2 = 0; f2 < 8; ++f2)
            bhi[f2] = *(const short8*)&bp[(size_t)(8 + f2) * 512 + lane * 8];
        #pragma unroll
        for (int f2 = 0; f2 < 8; ++f2) {
            a0 = __builtin_amdgcn_mfma_f32_32x32x16_bf16(af[0][f2], blo[f2], a0, 0, 0, 0);
            a1 = __builtin_amdgcn_mfma_f32_32x32x16_bf16(af[1][f2], blo[f2], a1, 0, 0, 0);
        }
        #pragma unroll
        for (int f2 = 0; f2 < 8; ++f2) {
            a0 = __builtin_amdgcn_mfma_f32_32x32x16_bf16(af[0][8 + f2], bhi[f2], a0, 0, 0, 0);
            a1 = __builtin_amdgcn_mfma_f32_32x32x16_bf16(af[1][8 + f2], bhi[f2], a1, 0, 0, 0);
        }
    };

    // ---- G1: score chunks (cw=0: {0,2}; cw=1: {1}) ----
    #pragma unroll
    for (int q = 0; q < 2; ++q) {
        const int c = cw + 2 * q;
        if (c > 2) continue;                       // wave-uniform
        floatx16 a0 = ZEROV, a1 = ZEROV;
        mm2(wPk + (size_t)c * 8192, a0, a1);
        const int col = 32 * c + ln;
        const bool valid = col < NCLS;
        const float bias = b_score[valid ? col : 0];
        #pragma unroll
        for (int tt = 0; tt < 2; ++tt) {
            const floatx16 acc = tt ? a1 : a0;
            #pragma unroll
            for (int r = 0; r < 16; ++r) {
                const int row = (r & 3) + 8 * (r >> 2) + 4 * half;
                float v = valid ? (acc[r] + bias) : -1e30f;
                if (valid)
                    out_logits[(size_t)(gt00 + 64 * tw + 32 * tt + row) * NCLS + col] = v;
                v = fmaxf(v, __shfl_xor(v, 1));
                v = fmaxf(v, __shfl_xor(v, 2));
                v = fmaxf(v, __shfl_xor(v, 4));
                v = fmaxf(v, __shfl_xor(v, 8));
                v = fmaxf(v, __shfl_xor(v, 16));   // stays within 32-lane half
                if (ln == 0) {
                    float* slot = &smax_s[cw][64 * tw + 32 * tt + row];
                    *slot = (q == 0) ? v : fmaxf(*slot, v);   // owner RMW, no race
                }
            }
        }
    }

    // ---- G2: w1 chunks (4 per wave) -> h1 in LDS ----
    #pragma unroll
    for (int q = 0; q < 4; ++q) {
        const int c = 3 + cw + 2 * q;
        floatx16 a0 = ZEROV, a1 = ZEROV;
        mm2(wPk + (size_t)c * 8192, a0, a1);
        const int col = 32 * (c - 3) + ln;
        const float bias = b1[col];
        #pragma unroll
        for (int tt = 0; tt < 2; ++tt) {
            const floatx16 acc = tt ? a1 : a0;
            #pragma unroll
            for (int r = 0; r < 16; ++r) {
                const int row = (r & 3) + 8 * (r >> 2) + 4 * half;
                const int tok = 64 * tw + 32 * tt + row;
                h1b[H1S(tok, col)] = f2bf(fmaxf(acc[r] + bias, 0.f));
            }
        }
    }
    __syncthreads();                               // B1: h1 + smax complete

    if (t < TBLK)
        ws_scores[gt00 + t] = sigmoidf_(fmaxf(smax_s[0][t], smax_s[1][t]));

    // ---- A2 fragments from h1 (swizzled b128) ----
    #pragma unroll
    for (int tt = 0; tt < 2; ++tt) {
        const int tok = 64 * tw + 32 * tt + ln;
        #pragma unroll
        for (int f = 0; f < 16; ++f) {
            const int ch = 2 * f + half;
            af[tt][f] = *(const short8*)&h1b[(tok << 8) + ((ch ^ (tok & 7)) << 3)];
        }
    }
    __syncthreads();                               // B2: A2 reads done, h2 may overwrite

    // ---- G3: w2 chunks (4 per wave) -> h2 (same buffer/swizzle) ----
    #pragma unroll
    for (int q = 0; q < 4; ++q) {
        const int c = 11 + cw + 2 * q;
        floatx16 a0 = ZEROV, a1 = ZEROV;
        mm2(wPk + (size_t)c * 8192, a0, a1);
        const int col = 32 * (c - 11) + ln;
        const float bias = b2[col];
        #pragma unroll
        for (int tt = 0; tt < 2; ++tt) {
            const floatx16 acc = tt ? a1 : a0;
            #pragma unroll
            for (int r = 0; r < 16; ++r) {
                const int row = (r & 3) + 8 * (r >> 2) + 4 * half;
                const int tok = 64 * tw + 32 * tt + row;
                h1b[H1S(tok, col)] = f2bf(fmaxf(acc[r] + bias, 0.f));
            }
        }
    }
    __syncthreads();                               // B3: h2 complete

    // ---- boxes: one MFMA chunk vs zero-padded packed w3 (wave owns 32 tokens) ----
    {
        const int tokb = 64 * tw + 32 * cw;
        const int tok = tokb + ln;
        #pragma unroll
        for (int f = 0; f < 16; ++f) {
            const int ch = 2 * f + half;
            af[0][f] = *(const short8*)&h1b[(tok << 8) + ((ch ^ (tok & 7)) << 3)];
        }
        short8 blo[8], bhi[8];
        #pragma unroll
        for (int f2 = 0; f2 < 8; ++f2)
            blo[f2] = *(const short8*)&w3Pk[(size_t)f2 * 512 + lane * 8];
        #pragma unroll
        for (int f2 = 0; f2 < 8; ++f2)
            bhi[f2] = *(const short8*)&w3Pk[(size_t)(8 + f2) * 512 + lane * 8];
        floatx16 acc = ZEROV;
        #pragma unroll
        for (int f2 = 0; f2 < 8; ++f2)
            acc = __builtin_amdgcn_mfma_f32_32x32x16_bf16(af[0][f2], blo[f2], acc, 0, 0, 0);
        #pragma unroll
        for (int f2 = 0; f2 < 8; ++f2)
            acc = __builtin_amdgcn_mfma_f32_32x32x16_bf16(af[0][8 + f2], bhi[f2], acc, 0, 0, 0);
        const float b3v = b3[ln & 3];
        if (ln < 4) {
            #pragma unroll
            for (int r = 0; r < 16; ++r) {
                const int row = (r & 3) + 8 * (r >> 2) + 4 * half;
                out_sboxes[(size_t)(gt00 + tokb + row) * 4 + ln] = sigmoidf_(acc[r] + b3v);
            }
        }
    }
}

// -------- Kernel 2: fp32 radix pre-select of top-KSEL candidates per batch --------
__global__ __launch_bounds__(256) void select_kernel(
    const float* __restrict__ scores,
    int* __restrict__ cand_idx, unsigned int* __restrict__ cand_cnt)
{
    const int bb = blockIdx.x;
    const int t = threadIdx.x;
    const int lane = t & 63;
    const float* s = scores + bb * NTOK;

    __shared__ unsigned int hist[256];
    __shared__ unsigned int prefix_s, rem_s, cnt_s;

    unsigned int prefix = 0, mask = 0;
    int remaining = KSEL;
    for (int pass = 0; pass < 4; pass++) {
        const int shift = 24 - 8 * pass;
        hist[t] = 0;
        __syncthreads();
        for (int n = t; n < NTOK; n += 256) {
            const unsigned int key = __float_as_uint(s[n]);
            const bool pred = ((key & mask) == prefix);
            const unsigned int bin = pred ? ((key >> shift) & 255u) : 0xFFFFu;
            const unsigned long long alive = __ballot(pred);
            if (alive) {
                const int leader = __builtin_ctzll(alive);
                const unsigned int lbin = (unsigned int)__shfl((int)bin, leader);
                const unsigned long long match = __ballot(pred && bin == lbin);
                if (lane == leader)
                    atomicAdd(&hist[lbin], (unsigned int)__popcll(match));
                else if (pred && bin != lbin)
                    atomicAdd(&hist[bin], 1u);
            }
        }
        __syncthreads();
        if (t == 0) {
            int rem = remaining; unsigned int bsel = 0;
            for (int bin = 255; bin >= 0; bin--) {
                int c = (int)hist[bin];
                if (c >= rem) { bsel = (unsigned int)bin; break; }
                rem -= c;
            }
            prefix_s = prefix | (bsel << shift);
            rem_s = (unsigned int)rem;
        }
        __syncthreads();
        prefix = prefix_s; remaining = (int)rem_s;
        mask |= 0xFFu << shift;
        __syncthreads();
    }
    const unsigned int Tkey = prefix;

    if (t == 0) cnt_s = 0;
    __syncthreads();
    for (int n = t; n < NTOK; n += 256) {
        const unsigned int key = __float_as_uint(s[n]);
        const bool pred = (key >= Tkey);
        const unsigned long long m = __ballot(pred);
        if (m) {
            const int leader = __builtin_ctzll(m);
            unsigned int base = 0;
            if (lane == leader) base = atomicAdd(&cnt_s, (unsigned int)__popcll(m));
            base = (unsigned int)__shfl((int)base, leader);
            if (pred) {
                const unsigned int pos =
                    base + (unsigned int)__popcll(m & ((1ull << lane) - 1ull));
                if (pos < CANDMAX) cand_idx[bb * CANDMAX + pos] = n;
            }
        }
    }
    __syncthreads();
    if (t == 0) {
        unsigned int c = cnt_s; if (c > CANDMAX) c = CANDMAX;
        cand_cnt[bb] = c;
    }
}

// -------- Kernel 3: f64 exact rescore (one wave per candidate) --------
__global__ __launch_bounds__(256) void rescore_kernel(
    const float* __restrict__ s3, const float* __restrict__ s4, const float* __restrict__ s5,
    const float* __restrict__ w_score, const float* __restrict__ b_score,
    const int* __restrict__ cand_idx, const unsigned int* __restrict__ cand_cnt,
    double* __restrict__ cand_score)
{
    __shared__ float mrow[4][CDIM];
    const int t = threadIdx.x;
    const int w = t >> 6;
    const int lane = t & 63;
    const int bb = blockIdx.x / (CANDMAX / 4);
    const int c  = (blockIdx.x % (CANDMAX / 4)) * 4 + w;
    const unsigned int cnt = cand_cnt[bb];
    const bool active = (unsigned int)c < cnt;

    int n = 0;
    if (active) n = cand_idx[bb * CANDMAX + c];
    if (active) {
        const float* src; int nloc, lsz;
        locate_level(n, bb, s3, s4, s5, src, nloc, lsz);
        #pragma unroll
        for (int j = 0; j < 4; j++)
            mrow[w][4 * lane + j] = src[(size_t)(4 * lane + j) * lsz + nloc];
    }
    __syncthreads();

    if (active) {
        double acc0 = (double)b_score[lane];
        double acc1 = (lane < 16) ? (double)b_score[64 + lane] : -1.0e300;
        for (int k = 0; k < CDIM; k++) {
            const double m = (double)mrow[w][k];
            acc0 += m * (double)w_score[k * NCLS + lane];
            if (lane < 16) acc1 += m * (double)w_score[k * NCLS + 64 + lane];
        }
        double mx = fmax(acc0, acc1);
        mx = fmax(mx, __shfl_xor(mx, 1));
        mx = fmax(mx, __shfl_xor(mx, 2));
        mx = fmax(mx, __shfl_xor(mx, 4));
        mx = fmax(mx, __shfl_xor(mx, 8));
        mx = fmax(mx, __shfl_xor(mx, 16));
        mx = fmax(mx, __shfl_xor(mx, 32));
        if (lane == 0) cand_score[bb * CANDMAX + c] = mx;
    }
}

// -------- Kernel 4: exact sort of candidates, emit top-300 --------
__global__ __launch_bounds__(256) void fsort_kernel(
    const double* __restrict__ cand_score, const int* __restrict__ cand_idx,
    const unsigned int* __restrict__ cand_cnt,
    float* __restrict__ out_idx_f, float* __restrict__ out_scores,
    int* __restrict__ ws_idx)
{
    __shared__ double ss[CANDMAX];
    __shared__ int    ii[CANDMAX];
    const int bb = blockIdx.x;
    const int t = threadIdx.x;
    const unsigned int cnt = cand_cnt[bb];

    for (int i = t; i < CANDMAX; i += 256) {
        if ((unsigned int)i < cnt) {
            ss[i] = cand_score[bb * CANDMAX + i];
            ii[i] = cand_idx[bb * CANDMAX + i];
        } else {
            ss[i] = -1.0e300;
            ii[i] = 0x7FFFFFFF;
        }
    }
    __syncthreads();

    for (int ksz = 2; ksz <= CANDMAX; ksz <<= 1) {
        for (int j = ksz >> 1; j > 0; j >>= 1) {
            #pragma unroll
            for (int p = 0; p < CANDMAX / 256; p++) {
                const int i = p * 256 + t;
                const int ixj = i ^ j;
                if (ixj > i) {
                    double sa = ss[i], sb = ss[ixj];
                    int ia = ii[i], ib = ii[ixj];
                    const bool up = ((i & ksz) != 0);
                    const bool agtb = (sa > sb) || (sa == sb && ia < ib);
                    if (agtb == up) { ss[i] = sb; ss[ixj] = sa; ii[i] = ib; ii[ixj] = ia; }
                }
            }
            __syncthreads();
        }
    }

    for (int q = t; q < KQ; q += 256) {
        const double x = ss[q];
        const int idx = ii[q];
        out_scores[bb * KQ + q] = (float)(1.0 / (1.0 + exp(-x)));
        out_idx_f[bb * KQ + q] = (float)idx;
        ws_idx[bb * KQ + q] = idx;
    }
}

// -------- Kernel 5: gather top-k memory rows, project, gather ref_points --------
__global__ __launch_bounds__(256) void gather_proj_kernel(
    const float* __restrict__ s3, const float* __restrict__ s4, const float* __restrict__ s5,
    const float* __restrict__ w_proj, const float* __restrict__ b_proj,
    const int* __restrict__ ws_idx, const float* __restrict__ out_sboxes,
    float* __restrict__ out_tgt, float* __restrict__ out_ref)
{
    __shared__ float memQ[20][CDIM];
    __shared__ int qidx[20];
    const int t = threadIdx.x;
    const int bb = blockIdx.x / 15;
    const int tile = blockIdx.x % 15;
    const int q0 = tile * 20;

    if (t < 20) qidx[t] = ws_idx[bb * KQ + q0 + t];
    __syncthreads();

    #pragma unroll 4
    for (int q = 0; q < 20; q++) {
        const int n = qidx[q];
        const float* src; int nloc, lsz;
        locate_level(n, bb, s3, s4, s5, src, nloc, lsz);
        memQ[q][t] = src[(size_t)t * lsz + nloc];
    }
    __syncthreads();

    const int j = t;
    float acc[20];
    #pragma unroll
    for (int q = 0; q < 20; q++) acc[q] = b_proj[j];
    for (int k = 0; k < CDIM; k++) {
        const float w = w_proj[(size_t)k * CDIM + j];
        #pragma unroll
        for (int q = 0; q < 20; q++) acc[q] = fmaf(memQ[q][k], w, acc[q]);
    }
    #pragma unroll
    for (int q = 0; q < 20; q++)
        out_tgt[(size_t)(bb * KQ + q0 + q) * CDIM + j] = acc[q];

    if (t < 80) {
        const int q = t >> 2, c = t & 3;
        const int n = qidx[q];
        out_ref[(size_t)(bb * KQ + q0 + q) * 4 + c] =
            out_sboxes[(size_t)(bb * NTOK + n) * 4 + c];
    }
}

extern "C" void kernel_launch(void* const* d_in, const int* in_sizes, int n_in,
                              void* d_out, int out_size, void* d_ws, size_t ws_size,
                              hipStream_t stream) {
    const float* s3      = (const float*)d_in[0];
    const float* s4      = (const float*)d_in[1];
    const float* s5      = (const float*)d_in[2];
    const float* w_score = (const float*)d_in[3];
    const float* b_score = (const float*)d_in[4];
    const float* w1      = (const float*)d_in[5];
    const float* b1      = (const float*)d_in[6];
    const float* w2      = (const float*)d_in[7];
    const float* b2      = (const float*)d_in[8];
    const float* w3      = (const float*)d_in[9];
    const float* b3      = (const float*)d_in[10];
    const float* w_proj  = (const float*)d_in[11];
    const float* b_proj  = (const float*)d_in[12];

    float* out = (float*)d_out;
    float* out_tgt    = out;                 // 16*300*256
    float* out_ref    = out + 1228800;       // 16*300*4
    float* out_logits = out + 1248000;       // 16*21504*80
    float* out_sboxes = out + 28773120;      // 16*21504*4
    float* out_idx    = out + 30149376;      // 16*300 (as float)
    float* out_scores = out + 30154176;      // 16*300

    char* ws = (char*)d_ws;
    float*        ws_scores  = (float*)(ws + 0);            // 1,376,256
    double*       cand_score = (double*)(ws + 1376256);     //   131,072
    int*          cand_idx   = (int*)(ws + 1507328);        //    65,536
    unsigned int* cand_cnt   = (unsigned int*)(ws + 1572864); //      256
    int*          ws_idx     = (int*)(ws + 1573120);        //    19,456
    ushort_t*     wPk        = (ushort_t*)(ws + 1592576);   //   311,296 (19*16KB)
    // w3Pk (16 KB) overlaps cand_score: lifetimes disjoint
    // (prep->enc use w3Pk; rescore->fsort use cand_score, strictly after enc)
    ushort_t*     w3Pk       = (ushort_t*)(ws + 1376256);

    prep_weights<<<20, 256, 0, stream>>>(w1, w2, w_score, w3, wPk, w3Pk);

    enc_mfma_kernel<<<BATCH * NBLK, 256, 0, stream>>>(
        s3, s4, s5, wPk, w3Pk, b_score, b1, b2, b3,
        out_logits, out_sboxes, ws_scores);

    select_kernel<<<BATCH, 256, 0, stream>>>(ws_scores, cand_idx, cand_cnt);

    rescore_kernel<<<BATCH * (CANDMAX / 4), 256, 0, stream>>>(
        s3, s4, s5, w_score, b_score, cand_idx, cand_cnt, cand_score);

    fsort_kernel<<<BATCH, 256, 0, stream>>>(
        cand_score, cand_idx, cand_cnt, out_idx, out_scores, ws_idx);

    gather_proj_kernel<<<BATCH * 15, 256, 0, stream>>>(
        s3, s4, s5, w_proj, b_proj, ws_idx, out_sboxes, out_tgt, out_ref);
}

// Round 4
// 1019.773 us; speedup vs baseline: 1.2899x; 1.2899x over previous
//
#include <hip/hip_runtime.h>
#include <math.h>

#define BATCH 16
#define CDIM 256
#define NCLS 80
#define N3 16384
#define N4 4096
#define N5 1024
#define NTOK 21504
#define KQ 300
#define KSEL 512
#define CANDMAX 1024

typedef __attribute__((ext_vector_type(8))) short short8;
typedef __attribute__((ext_vector_type(4))) float floatx4;
typedef unsigned short ushort_t;

__device__ __forceinline__ float sigmoidf_(float x) {
    return 1.0f / (1.0f + __expf(-x));
}

__device__ __forceinline__ ushort_t f2bf(float f) {   // RNE f32->bf16
    unsigned int x = __float_as_uint(f);
    unsigned int r = (x + 0x7FFFu + ((x >> 16) & 1u)) >> 16;
    return (ushort_t)r;
}

__device__ __forceinline__ void gload16(const void* g, void* l) {
    __builtin_amdgcn_global_load_lds(
        (const __attribute__((address_space(1))) unsigned int*)g,
        (__attribute__((address_space(3))) unsigned int*)l,
        16, 0, 0);
}

__device__ __forceinline__ void locate_level(
    int n, int bb,
    const float* __restrict__ s3, const float* __restrict__ s4, const float* __restrict__ s5,
    const float*& src, int& nloc, int& lsz)
{
    if (n < N3)           { src = s3 + (size_t)bb * CDIM * N3; nloc = n;           lsz = N3; }
    else if (n < N3 + N4) { src = s4 + (size_t)bb * CDIM * N4; nloc = n - N3;      lsz = N4; }
    else                  { src = s5 + (size_t)bb * CDIM * N5; nloc = n - N3 - N4; lsz = N5; }
}

// -------- Kernel 0: transpose+cast weights to bf16 W^T[col][k], PRE-SWIZZLED --------
// (R1 verbatim — feeds the known-good 318us enc kernel)
__global__ __launch_bounds__(256) void prep_weights(
    const float* __restrict__ w1, const float* __restrict__ w2,
    const float* __restrict__ w_score,
    ushort_t* __restrict__ w1T, ushort_t* __restrict__ w2T, ushort_t* __restrict__ wsT)
{
    const int k = threadIdx.x;
    const int c = blockIdx.x;
    const int klo = k & 7;
    if (c < 256) {
        const size_t d = (size_t)c * 256 + ((((k >> 3) ^ (c & 7)) << 3) | klo);
        w1T[d] = f2bf(w1[k * 256 + c]);
    } else if (c < 512) {
        const int c2 = c - 256;
        const size_t d = (size_t)c2 * 256 + ((((k >> 3) ^ (c2 & 7)) << 3) | klo);
        w2T[d] = f2bf(w2[k * 256 + c2]);
    } else {
        const int c2 = c - 512;
        const size_t d = (size_t)c2 * 256 + ((((k >> 3) ^ (c2 & 7)) << 3) | klo);
        wsT[d] = (c2 < NCLS) ? f2bf(w_score[k * NCLS + c2]) : (ushort_t)0;
    }
}

// -------- Kernel 1: fused encoder head (R1 verbatim: 318us, 88 VGPR, no spill) --------
__global__ __launch_bounds__(256, 2) void enc_mfma_kernel(
    const float* __restrict__ s3, const float* __restrict__ s4, const float* __restrict__ s5,
    const ushort_t* __restrict__ w1T, const ushort_t* __restrict__ w2T,
    const ushort_t* __restrict__ wsT,
    const float* __restrict__ b_score, const float* __restrict__ b1,
    const float* __restrict__ b2,
    const float* __restrict__ w3, const float* __restrict__ b3,
    float* __restrict__ out_logits, float* __restrict__ out_sboxes,
    float* __restrict__ ws_scores)
{
    __shared__ __align__(16) ushort_t ldsA[256 * 68];       // 34816 B
    __shared__ __align__(16) ushort_t wbufL[2][32 * 256];   // 2 x 16384 B (linear, DMA dest)
    __shared__ float bsc_s[96];
    __shared__ float b1_s[256];
    __shared__ float b2_s[256];
    __shared__ __align__(16) float w3_s[256 * 4];

    const int t = threadIdx.x;
    const int lane = t & 63;
    const int w = t >> 6;
    const int ml = lane & 15;
    const int quad = lane >> 4;
    const int kq = quad * 8;
    const int m8 = ml & 7;

    const int bb = blockIdx.x / 336;
    const int tile = blockIdx.x % 336;
    const int T0 = tile * 64;

    auto stage_async = [&](const ushort_t* wg, int dbuf) {
        const char* g = (const char*)wg + w * 1024 + (lane << 4);
        char* l = (char*)&wbufL[dbuf][0] + w * 1024;
        #pragma unroll
        for (int i = 0; i < 4; ++i)
            gload16(g + i * 4096, l + i * 4096);
    };

    stage_async(wsT, 0);

    if (t < 96) bsc_s[t] = b_score[t];
    b1_s[t] = b1[t];
    b2_s[t] = b2[t];
    *(float4*)&w3_s[t * 4] = *(const float4*)(w3 + t * 4);

    const float* src; int nloc, lsz;
    locate_level(T0, bb, s3, s4, s5, src, nloc, lsz);

    {
        const int tokq = t & 15;
        const int kr = t >> 4;
        #pragma unroll
        for (int p = 0; p < 16; ++p) {
            const int k = p * 16 + kr;
            const float4 v = *(const float4*)(src + (size_t)k * lsz + nloc + 4 * tokq);
            const unsigned int lo = (unsigned int)f2bf(v.x) | ((unsigned int)f2bf(v.y) << 16);
            const unsigned int hi = (unsigned int)f2bf(v.z) | ((unsigned int)f2bf(v.w) << 16);
            *(uint2*)&ldsA[k * 68 + 4 * tokq] = make_uint2(lo, hi);
        }
    }
    __syncthreads();

    short8 af[8];
    #pragma unroll
    for (int f = 0; f < 8; ++f) {
        short8 a;
        #pragma unroll
        for (int j = 0; j < 8; ++j)
            a[j] = (short)ldsA[(32 * f + kq + j) * 68 + 16 * w + ml];
        af[f] = a;
    }

    const int tokl0 = 16 * w + quad * 4;
    const int tokg0 = bb * NTOK + T0 + tokl0;

    float smax[4] = {-1e30f, -1e30f, -1e30f, -1e30f};
    float psum[4][4];
    #pragma unroll
    for (int r = 0; r < 4; ++r)
        #pragma unroll
        for (int c = 0; c < 4; ++c) psum[r][c] = 0.f;

    int cur = 0;
    for (int i = 0; i < 19; ++i) {
        if (i + 1 < 19) {
            const int j = i + 1;
            const ushort_t* nxt = (j < 3)  ? (wsT + (size_t)j * 8192)
                                : (j < 11) ? (w1T + (size_t)(j - 3) * 8192)
                                           : (w2T + (size_t)(j - 11) * 8192);
            stage_async(nxt, cur ^ 1);
        }

        if (i == 11) {
            #pragma unroll
            for (int f = 0; f < 8; ++f)
                af[f] = *(const short8*)&ldsA[(16 * w + ml) * 264 + 32 * f + kq];
        }

        const ushort_t* wb = &wbufL[cur][0];
        #pragma unroll
        for (int tt = 0; tt < 2; ++tt) {
            if (i < 3 && (2 * i + tt) >= 5) continue;
            const int row = 16 * tt + ml;
            floatx4 acc = {0.f, 0.f, 0.f, 0.f};
            #pragma unroll
            for (int f = 0; f < 8; ++f) {
                const short8 bf = *(const short8*)&wb[row * 256 + (((4 * f + quad) ^ m8) << 3)];
                acc = __builtin_amdgcn_mfma_f32_16x16x32_bf16(af[f], bf, acc, 0, 0, 0);
            }
            if (i < 3) {
                const int col = 16 * (2 * i + tt) + ml;
                const float bias = bsc_s[col];
                #pragma unroll
                for (int r = 0; r < 4; ++r) {
                    const float v = acc[r] + bias;
                    out_logits[(size_t)(tokg0 + r) * NCLS + col] = v;
                    smax[r] = fmaxf(smax[r], v);
                }
            } else if (i < 11) {
                const int col = 32 * (i - 3) + 16 * tt + ml;
                const float bias = b1_s[col];
                #pragma unroll
                for (int r = 0; r < 4; ++r) {
                    const float v = fmaxf(acc[r] + bias, 0.f);
                    ldsA[(tokl0 + r) * 264 + col] = f2bf(v);
                }
            } else {
                const int col = 32 * (i - 11) + 16 * tt + ml;
                const float bias = b2_s[col];
                const float4 w3v = *(const float4*)&w3_s[col * 4];
                #pragma unroll
                for (int r = 0; r < 4; ++r) {
                    const float v = fmaxf(acc[r] + bias, 0.f);
                    psum[r][0] = fmaf(v, w3v.x, psum[r][0]);
                    psum[r][1] = fmaf(v, w3v.y, psum[r][1]);
                    psum[r][2] = fmaf(v, w3v.z, psum[r][2]);
                    psum[r][3] = fmaf(v, w3v.w, psum[r][3]);
                }
            }
        }

        if (i == 2) {
            #pragma unroll
            for (int r = 0; r < 4; ++r) {
                float m = smax[r];
                m = fmaxf(m, __shfl_xor(m, 1));
                m = fmaxf(m, __shfl_xor(m, 2));
                m = fmaxf(m, __shfl_xor(m, 4));
                m = fmaxf(m, __shfl_xor(m, 8));
                smax[r] = m;
            }
            if (ml == 0) {
                #pragma unroll
                for (int r = 0; r < 4; ++r)
                    ws_scores[bb * NTOK + T0 + 16 * w + quad * 4 + r] = sigmoidf_(smax[r]);
            }
        }

        __syncthreads();
        cur ^= 1;
    }

    #pragma unroll
    for (int r = 0; r < 4; ++r)
        #pragma unroll
        for (int c = 0; c < 4; ++c) {
            float v = psum[r][c];
            v += __shfl_xor(v, 1);
            v += __shfl_xor(v, 2);
            v += __shfl_xor(v, 4);
            v += __shfl_xor(v, 8);
            psum[r][c] = v;
        }
    if (ml == 0) {
        #pragma unroll
        for (int r = 0; r < 4; ++r) {
            float4 o;
            o.x = sigmoidf_(psum[r][0] + b3[0]);
            o.y = sigmoidf_(psum[r][1] + b3[1]);
            o.z = sigmoidf_(psum[r][2] + b3[2]);
            o.w = sigmoidf_(psum[r][3] + b3[3]);
            *(float4*)&out_sboxes[(size_t)(bb * NTOK + T0 + 16 * w + quad * 4 + r) * 4] = o;
        }
    }
}

// -------- Kernel 2: fp32 radix pre-select of top-KSEL candidates per batch --------
__global__ __launch_bounds__(256) void select_kernel(
    const float* __restrict__ scores,
    int* __restrict__ cand_idx, unsigned int* __restrict__ cand_cnt)
{
    const int bb = blockIdx.x;
    const int t = threadIdx.x;
    const int lane = t & 63;
    const float* s = scores + bb * NTOK;

    __shared__ unsigned int hist[256];
    __shared__ unsigned int prefix_s, rem_s, cnt_s;

    unsigned int prefix = 0, mask = 0;
    int remaining = KSEL;
    for (int pass = 0; pass < 4; pass++) {
        const int shift = 24 - 8 * pass;
        hist[t] = 0;
        __syncthreads();
        for (int n = t; n < NTOK; n += 256) {
            const unsigned int key = __float_as_uint(s[n]);
            const bool pred = ((key & mask) == prefix);
            const unsigned int bin = pred ? ((key >> shift) & 255u) : 0xFFFFu;
            const unsigned long long alive = __ballot(pred);
            if (alive) {
                const int leader = __builtin_ctzll(alive);
                const unsigned int lbin = (unsigned int)__shfl((int)bin, leader);
                const unsigned long long match = __ballot(pred && bin == lbin);
                if (lane == leader)
                    atomicAdd(&hist[lbin], (unsigned int)__popcll(match));
                else if (pred && bin != lbin)
                    atomicAdd(&hist[bin], 1u);
            }
        }
        __syncthreads();
        if (t == 0) {
            int rem = remaining; unsigned int bsel = 0;
            for (int bin = 255; bin >= 0; bin--) {
                int c = (int)hist[bin];
                if (c >= rem) { bsel = (unsigned int)bin; break; }
                rem -= c;
            }
            prefix_s = prefix | (bsel << shift);
            rem_s = (unsigned int)rem;
        }
        __syncthreads();
        prefix = prefix_s; remaining = (int)rem_s;
        mask |= 0xFFu << shift;
        __syncthreads();
    }
    const unsigned int Tkey = prefix;

    if (t == 0) cnt_s = 0;
    __syncthreads();
    for (int n = t; n < NTOK; n += 256) {
        const unsigned int key = __float_as_uint(s[n]);
        const bool pred = (key >= Tkey);
        const unsigned long long m = __ballot(pred);
        if (m) {
            const int leader = __builtin_ctzll(m);
            unsigned int base = 0;
            if (lane == leader) base = atomicAdd(&cnt_s, (unsigned int)__popcll(m));
            base = (unsigned int)__shfl((int)base, leader);
            if (pred) {
                const unsigned int pos =
                    base + (unsigned int)__popcll(m & ((1ull << lane) - 1ull));
                if (pos < CANDMAX) cand_idx[bb * CANDMAX + pos] = n;
            }
        }
    }
    __syncthreads();
    if (t == 0) {
        unsigned int c = cnt_s; if (c > CANDMAX) c = CANDMAX;
        cand_cnt[bb] = c;
    }
}

// -------- Kernel 3: f64 exact rescore, ONE BLOCK PER CANDIDATE --------
// 256-thread parallel gather (one round of loads, 4x the MLP of the old 1-wave
// version), 2-way k-split f64 dot over 80 cols, exact f32 row saved to cand_mem
// (coalesced) for gather_proj reuse.
__global__ __launch_bounds__(256) void rescore_kernel(
    const float* __restrict__ s3, const float* __restrict__ s4, const float* __restrict__ s5,
    const float* __restrict__ w_score, const float* __restrict__ b_score,
    const int* __restrict__ cand_idx, const unsigned int* __restrict__ cand_cnt,
    double* __restrict__ cand_score, float* __restrict__ cand_mem, int use_cmem)
{
    __shared__ float m_s[CDIM];
    __shared__ double part[256];

    const int t = threadIdx.x;
    const int bb = blockIdx.x / CANDMAX;
    const int cpos = blockIdx.x % CANDMAX;
    if ((unsigned int)cpos >= cand_cnt[bb]) return;

    const int n = cand_idx[bb * CANDMAX + cpos];
    const float* src; int nloc, lsz;
    locate_level(n, bb, s3, s4, s5, src, nloc, lsz);
    m_s[t] = src[(size_t)t * lsz + nloc];
    __syncthreads();

    if (use_cmem)
        cand_mem[((size_t)bb * CANDMAX + cpos) * CDIM + t] = m_s[t];

    const int ks = t >> 7;          // k-slice 0/1 (128 k each)
    const int c = t & 127;          // column
    double acc = 0.0;
    if (c < NCLS) {
        if (ks == 0) acc = (double)b_score[c];
        const int k0 = 128 * ks;
        for (int k = k0; k < k0 + 128; ++k)
            acc += (double)m_s[k] * (double)w_score[k * NCLS + c];
    }
    part[t] = acc;
    __syncthreads();

    if (t < 128) {
        double tot = (t < NCLS) ? (part[t] + part[t + 128]) : -1.0e300;
        part[t] = tot;
    }
    __syncthreads();

    if (t < 64) {
        double v = fmax(part[t], part[t + 64]);
        v = fmax(v, __shfl_xor(v, 1));
        v = fmax(v, __shfl_xor(v, 2));
        v = fmax(v, __shfl_xor(v, 4));
        v = fmax(v, __shfl_xor(v, 8));
        v = fmax(v, __shfl_xor(v, 16));
        v = fmax(v, __shfl_xor(v, 32));
        if (t == 0) cand_score[bb * CANDMAX + cpos] = v;
    }
}

// -------- Kernel 4: exact sort of candidates, emit top-300 (+cand position) --------
__global__ __launch_bounds__(512) void fsort_kernel(
    const double* __restrict__ cand_score, const int* __restrict__ cand_idx,
    const unsigned int* __restrict__ cand_cnt,
    float* __restrict__ out_idx_f, float* __restrict__ out_scores,
    int* __restrict__ ws_idx, int* __restrict__ ws_pos)
{
    __shared__ double ss[CANDMAX];
    __shared__ int    ii[CANDMAX];
    __shared__ int    pp[CANDMAX];
    const int bb = blockIdx.x;
    const int t = threadIdx.x;
    const unsigned int cnt = cand_cnt[bb];

    for (int i = t; i < CANDMAX; i += 512) {
        if ((unsigned int)i < cnt) {
            ss[i] = cand_score[bb * CANDMAX + i];
            ii[i] = cand_idx[bb * CANDMAX + i];
        } else {
            ss[i] = -1.0e300;
            ii[i] = 0x7FFFFFFF;
        }
        pp[i] = i;
    }
    __syncthreads();

    for (int ksz = 2; ksz <= CANDMAX; ksz <<= 1) {
        for (int j = ksz >> 1; j > 0; j >>= 1) {
            #pragma unroll
            for (int p = 0; p < CANDMAX / 512; p++) {
                const int i = p * 512 + t;
                const int ixj = i ^ j;
                if (ixj > i) {
                    double sa = ss[i], sb = ss[ixj];
                    int ia = ii[i], ib = ii[ixj];
                    const bool up = ((i & ksz) != 0);
                    const bool agtb = (sa > sb) || (sa == sb && ia < ib);
                    if (agtb == up) {
                        ss[i] = sb; ss[ixj] = sa;
                        ii[i] = ib; ii[ixj] = ia;
                        const int pa = pp[i]; pp[i] = pp[ixj]; pp[ixj] = pa;
                    }
                }
            }
            __syncthreads();
        }
    }

    for (int q = t; q < KQ; q += 512) {
        const double x = ss[q];
        const int idx = ii[q];
        out_scores[bb * KQ + q] = (float)(1.0 / (1.0 + exp(-x)));
        out_idx_f[bb * KQ + q] = (float)idx;
        ws_idx[bb * KQ + q] = idx;
        ws_pos[bb * KQ + q] = pp[q];
    }
}

// -------- Kernel 5: gather top-k memory rows, project, gather ref_points --------
// Fast path: rows come packed+coalesced from cand_mem (written by rescore).
__global__ __launch_bounds__(256) void gather_proj_kernel(
    const float* __restrict__ s3, const float* __restrict__ s4, const float* __restrict__ s5,
    const float* __restrict__ w_proj, const float* __restrict__ b_proj,
    const int* __restrict__ ws_idx, const int* __restrict__ ws_pos,
    const float* __restrict__ cand_mem, int use_cmem,
    const float* __restrict__ out_sboxes,
    float* __restrict__ out_tgt, float* __restrict__ out_ref)
{
    __shared__ float memQ[20][CDIM];
    __shared__ int qidx[20];
    __shared__ int qpos[20];
    const int t = threadIdx.x;
    const int bb = blockIdx.x / 15;
    const int tile = blockIdx.x % 15;
    const int q0 = tile * 20;

    if (t < 20) {
        qidx[t] = ws_idx[bb * KQ + q0 + t];
        qpos[t] = ws_pos[bb * KQ + q0 + t];
    }
    __syncthreads();

    if (use_cmem) {
        #pragma unroll 4
        for (int q = 0; q < 20; q++)
            memQ[q][t] = cand_mem[((size_t)bb * CANDMAX + qpos[q]) * CDIM + t];
    } else {
        #pragma unroll 4
        for (int q = 0; q < 20; q++) {
            const int n = qidx[q];
            const float* src; int nloc, lsz;
            locate_level(n, bb, s3, s4, s5, src, nloc, lsz);
            memQ[q][t] = src[(size_t)t * lsz + nloc];
        }
    }
    __syncthreads();

    const int j = t;
    float acc[20];
    #pragma unroll
    for (int q = 0; q < 20; q++) acc[q] = b_proj[j];
    for (int k = 0; k < CDIM; k++) {
        const float w = w_proj[(size_t)k * CDIM + j];
        #pragma unroll
        for (int q = 0; q < 20; q++) acc[q] = fmaf(memQ[q][k], w, acc[q]);
    }
    #pragma unroll
    for (int q = 0; q < 20; q++)
        out_tgt[(size_t)(bb * KQ + q0 + q) * CDIM + j] = acc[q];

    if (t < 80) {
        const int q = t >> 2, c = t & 3;
        const int n = qidx[q];
        out_ref[(size_t)(bb * KQ + q0 + q) * 4 + c] =
            out_sboxes[(size_t)(bb * NTOK + n) * 4 + c];
    }
}

extern "C" void kernel_launch(void* const* d_in, const int* in_sizes, int n_in,
                              void* d_out, int out_size, void* d_ws, size_t ws_size,
                              hipStream_t stream) {
    const float* s3      = (const float*)d_in[0];
    const float* s4      = (const float*)d_in[1];
    const float* s5      = (const float*)d_in[2];
    const float* w_score = (const float*)d_in[3];
    const float* b_score = (const float*)d_in[4];
    const float* w1      = (const float*)d_in[5];
    const float* b1      = (const float*)d_in[6];
    const float* w2      = (const float*)d_in[7];
    const float* b2      = (const float*)d_in[8];
    const float* w3      = (const float*)d_in[9];
    const float* b3      = (const float*)d_in[10];
    const float* w_proj  = (const float*)d_in[11];
    const float* b_proj  = (const float*)d_in[12];

    float* out = (float*)d_out;
    float* out_tgt    = out;                 // 16*300*256
    float* out_ref    = out + 1228800;       // 16*300*4
    float* out_logits = out + 1248000;       // 16*21504*80
    float* out_sboxes = out + 28773120;      // 16*21504*4
    float* out_idx    = out + 30149376;      // 16*300 (as float)
    float* out_scores = out + 30154176;      // 16*300

    char* ws = (char*)d_ws;
    float*        ws_scores  = (float*)(ws + 0);              // 1,376,256
    double*       cand_score = (double*)(ws + 1376256);       //   131,072
    int*          cand_idx   = (int*)(ws + 1507328);          //    65,536
    unsigned int* cand_cnt   = (unsigned int*)(ws + 1572864); //       256
    int*          ws_idx     = (int*)(ws + 1573120);          //    19,456
    int*          ws_pos     = (int*)(ws + 1592576);          //    19,456
    ushort_t*     w1T        = (ushort_t*)(ws + 1612032);     //   131,072
    ushort_t*     w2T        = (ushort_t*)(ws + 1743104);     //   131,072
    ushort_t*     wsT        = (ushort_t*)(ws + 1874176);     //    49,152
    float*        cand_mem   = (float*)(ws + 1923328);        // 16,777,216
    const int use_cmem = (ws_size >= (size_t)1923328 + 16777216) ? 1 : 0;

    prep_weights<<<608, 256, 0, stream>>>(w1, w2, w_score, w1T, w2T, wsT);

    enc_mfma_kernel<<<BATCH * 336, 256, 0, stream>>>(
        s3, s4, s5, w1T, w2T, wsT, b_score, b1, b2, w3, b3,
        out_logits, out_sboxes, ws_scores);

    select_kernel<<<BATCH, 256, 0, stream>>>(ws_scores, cand_idx, cand_cnt);

    rescore_kernel<<<BATCH * CANDMAX, 256, 0, stream>>>(
        s3, s4, s5, w_score, b_score, cand_idx, cand_cnt,
        cand_score, cand_mem, use_cmem);

    fsort_kernel<<<BATCH, 512, 0, stream>>>(
        cand_score, cand_idx, cand_cnt, out_idx, out_scores, ws_idx, ws_pos);

    gather_proj_kernel<<<BATCH * 15, 256, 0, stream>>>(
        s3, s4, s5, w_proj, b_proj, ws_idx, ws_pos, cand_mem, use_cmem,
        out_sboxes, out_tgt, out_ref);
}

// Round 7
// 991.716 us; speedup vs baseline: 1.3264x; 1.0283x over previous
//
#include <hip/hip_runtime.h>
#include <math.h>

#define BATCH 16
#define CDIM 256
#define NCLS 80
#define N3 16384
#define N4 4096
#define N5 1024
#define NTOK 21504
#define KQ 300
#define KSEL 512
#define CANDMAX 1024

typedef __attribute__((ext_vector_type(8))) short short8;
typedef __attribute__((ext_vector_type(4))) float floatx4;
typedef unsigned short ushort_t;

// ldsA address (u16 units): [tok][264], 16B-chunk XOR-swizzled by tok&7.
// Used for BOTH the staged memory tile and the h1 round-trip.
#define LA(tok, k) (((tok) * 264) + (((((k) >> 3) ^ ((tok) & 7)) << 3) | ((k) & 7)))

__device__ __forceinline__ float sigmoidf_(float x) {
    return 1.0f / (1.0f + __expf(-x));
}

__device__ __forceinline__ ushort_t f2bf(float f) {   // RNE f32->bf16
    unsigned int x = __float_as_uint(f);
    unsigned int r = (x + 0x7FFFu + ((x >> 16) & 1u)) >> 16;
    return (ushort_t)r;
}

__device__ __forceinline__ void gload16(const void* g, void* l) {
    __builtin_amdgcn_global_load_lds(
        (const __attribute__((address_space(1))) unsigned int*)g,
        (__attribute__((address_space(3))) unsigned int*)l,
        16, 0, 0);
}

__device__ __forceinline__ void locate_level(
    int n, int bb,
    const float* __restrict__ s3, const float* __restrict__ s4, const float* __restrict__ s5,
    const float*& src, int& nloc, int& lsz)
{
    if (n < N3)           { src = s3 + (size_t)bb * CDIM * N3; nloc = n;           lsz = N3; }
    else if (n < N3 + N4) { src = s4 + (size_t)bb * CDIM * N4; nloc = n - N3;      lsz = N4; }
    else                  { src = s5 + (size_t)bb * CDIM * N5; nloc = n - N3 - N4; lsz = N5; }
}

// -------- Kernel 0: transpose+cast weights to bf16 W^T[col][k], PRE-SWIZZLED --------
__global__ __launch_bounds__(256) void prep_weights(
    const float* __restrict__ w1, const float* __restrict__ w2,
    const float* __restrict__ w_score,
    ushort_t* __restrict__ w1T, ushort_t* __restrict__ w2T, ushort_t* __restrict__ wsT)
{
    const int k = threadIdx.x;
    const int c = blockIdx.x;
    const int klo = k & 7;
    if (c < 256) {
        const size_t d = (size_t)c * 256 + ((((k >> 3) ^ (c & 7)) << 3) | klo);
        w1T[d] = f2bf(w1[k * 256 + c]);
    } else if (c < 512) {
        const int c2 = c - 256;
        const size_t d = (size_t)c2 * 256 + ((((k >> 3) ^ (c2 & 7)) << 3) | klo);
        w2T[d] = f2bf(w2[k * 256 + c2]);
    } else {
        const int c2 = c - 512;
        const size_t d = (size_t)c2 * 256 + ((((k >> 3) ^ (c2 & 7)) << 3) | klo);
        wsT[d] = (c2 < NCLS) ? f2bf(w_score[k * NCLS + c2]) : (ushort_t)0;
    }
}

// -------- Kernel 1: fused encoder head, M=32/wave, b128-only LDS traffic --------
// grid: BATCH*336 blocks (64 tokens), 256 threads = 4 waves.
// wave w: token-half tw=w&1 (2 tiles of 16), col-half cw=w>>1 (16 cols/chunk).
// Each B fragment (ds_read_b128) feeds 2 MFMAs; A fragments are b128 reads from
// the [tok][264] swizzled tile. 19-step DMA-double-buffered weight loop (R1).
__global__ __launch_bounds__(256, 2) void enc_mfma_kernel(
    const float* __restrict__ s3, const float* __restrict__ s4, const float* __restrict__ s5,
    const ushort_t* __restrict__ w1T, const ushort_t* __restrict__ w2T,
    const ushort_t* __restrict__ wsT,
    const float* __restrict__ b_score, const float* __restrict__ b1,
    const float* __restrict__ b2,
    const float* __restrict__ w3, const float* __restrict__ b3,
    float* __restrict__ out_logits, float* __restrict__ out_sboxes,
    float* __restrict__ ws_scores)
{
    __shared__ __align__(16) ushort_t ldsA[64 * 264];       // 33792 B: memB then h1
    __shared__ __align__(16) ushort_t wbufL[2][32 * 256];   // 32768 B (linear DMA dest)
    __shared__ float bsc_s[80];
    __shared__ float b1_s[256];
    __shared__ float b2_s[256];
    __shared__ __align__(16) float w3_s[256 * 4];
    __shared__ float smax_s[2][64];
    __shared__ __align__(16) float boxp[2][64][4];

    const int t = threadIdx.x;
    const int lane = t & 63;
    const int w = t >> 6;
    const int tw = w & 1;                 // token half: tiles {32tw, 32tw+16}
    const int cw = w >> 1;                // col half within each 32-col chunk
    const int ml = lane & 15;
    const int quad = lane >> 4;
    const int kq = quad * 8;
    const int m8 = ml & 7;

    const int bb = blockIdx.x / 336;
    const int tile_ = blockIdx.x % 336;
    const int T0 = tile_ * 64;

    auto stage_async = [&](const ushort_t* wg, int dbuf) {
        const char* g = (const char*)wg + w * 1024 + (lane << 4);
        char* l = (char*)&wbufL[dbuf][0] + w * 1024;      // wave-uniform LDS base
        #pragma unroll
        for (int i = 0; i < 4; ++i)
            gload16(g + i * 4096, l + i * 4096);
    };

    stage_async(wsT, 0);                  // chunk 0 DMA in flight during staging

    if (t < 80) bsc_s[t] = b_score[t];
    b1_s[t] = b1[t];
    b2_s[t] = b2[t];
    *(float4*)&w3_s[t * 4] = *(const float4*)(w3 + t * 4);

    const float* src; int nloc, lsz;
    locate_level(T0, bb, s3, s4, s5, src, nloc, lsz);

    // ---- stage memory tile TRANSPOSED: [k][tok] global -> [tok][k] LDS (swizzled) ----
    {
        const int tokq = t & 15;          // owns toks 4*tokq .. +3
        const int kg = t >> 4;            // 16 k-groups of 8
        #pragma unroll
        for (int p = 0; p < 2; ++p) {
            const int kbase = 8 * kg + 128 * p;
            float4 v[8];
            #pragma unroll
            for (int j = 0; j < 8; ++j)
                v[j] = *(const float4*)(src + (size_t)(kbase + j) * lsz + nloc + 4 * tokq);
            #pragma unroll
            for (int r = 0; r < 4; ++r) {
                short8 a;
                #pragma unroll
                for (int j = 0; j < 8; ++j)
                    a[j] = (short)f2bf(((const float*)&v[j])[r]);
                *(short8*)&ldsA[LA(4 * tokq + r, kbase)] = a;
            }
        }
    }
    __syncthreads();                      // memB + biases + chunk0 DMA ready

    // ---- A1 fragments: 16 x ds_read_b128 (row=tok=32tw+16tl+ml, k=32f+kq..+8) ----
    short8 af[2][8];
    #pragma unroll
    for (int tl = 0; tl < 2; ++tl) {
        const int tok = 32 * tw + 16 * tl + ml;
        #pragma unroll
        for (int f = 0; f < 8; ++f)
            af[tl][f] = *(const short8*)&ldsA[LA(tok, 32 * f + kq)];
    }

    const int gtok0 = bb * NTOK + T0;

    float smaxr[2][4];
    #pragma unroll
    for (int tl = 0; tl < 2; ++tl)
        #pragma unroll
        for (int r = 0; r < 4; ++r) smaxr[tl][r] = -1e30f;

    float psum[2][4][4];
    #pragma unroll
    for (int tl = 0; tl < 2; ++tl)
        #pragma unroll
        for (int r = 0; r < 4; ++r)
            #pragma unroll
            for (int c = 0; c < 4; ++c) psum[tl][r][c] = 0.f;

    int cur = 0;
    for (int i = 0; i < 19; ++i) {
        if (i + 1 < 19) {
            const int j = i + 1;
            const ushort_t* nxt = (j < 3)  ? (wsT + (size_t)j * 8192)
                                : (j < 11) ? (w1T + (size_t)(j - 3) * 8192)
                                           : (w2T + (size_t)(j - 11) * 8192);
            stage_async(nxt, cur ^ 1);
        }

        // A2 fragments from h1 (complete as of barrier at end of i==10)
        if (i == 11) {
            #pragma unroll
            for (int tl = 0; tl < 2; ++tl) {
                const int tok = 32 * tw + 16 * tl + ml;
                #pragma unroll
                for (int f = 0; f < 8; ++f)
                    af[tl][f] = *(const short8*)&ldsA[LA(tok, 32 * f + kq)];
            }
        }

        const ushort_t* wb = &wbufL[cur][0];
        const int row = 16 * cw + ml;     // wave's col within the 32-col chunk
        floatx4 acc0 = {0.f, 0.f, 0.f, 0.f};
        floatx4 acc1 = {0.f, 0.f, 0.f, 0.f};
        #pragma unroll
        for (int f = 0; f < 8; ++f) {
            const short8 bf = *(const short8*)&wb[row * 256 + (((4 * f + quad) ^ m8) << 3)];
            acc0 = __builtin_amdgcn_mfma_f32_16x16x32_bf16(af[0][f], bf, acc0, 0, 0, 0);
            acc1 = __builtin_amdgcn_mfma_f32_16x16x32_bf16(af[1][f], bf, acc1, 0, 0, 0);
        }

        if (i < 3) {
            // GEMM1: logits + running row max
            const int col = 32 * i + 16 * cw + ml;
            if (col < NCLS) {             // wave-uniform per (i,cw)
                const float bias = bsc_s[col];
                #pragma unroll
                for (int tl = 0; tl < 2; ++tl)
                    #pragma unroll
                    for (int r = 0; r < 4; ++r) {
                        const float v = (tl ? acc1[r] : acc0[r]) + bias;
                        const int ltok = 32 * tw + 16 * tl + 4 * quad + r;
                        out_logits[(size_t)(gtok0 + ltok) * NCLS + col] = v;
                        smaxr[tl][r] = fmaxf(smaxr[tl][r], v);
                    }
            }
            if (i == 2) {                 // reduce over the 16 col-lanes, stash
                #pragma unroll
                for (int tl = 0; tl < 2; ++tl)
                    #pragma unroll
                    for (int r = 0; r < 4; ++r) {
                        float m = smaxr[tl][r];
                        m = fmaxf(m, __shfl_xor(m, 1));
                        m = fmaxf(m, __shfl_xor(m, 2));
                        m = fmaxf(m, __shfl_xor(m, 4));
                        m = fmaxf(m, __shfl_xor(m, 8));
                        if (ml == 0)
                            smax_s[cw][32 * tw + 16 * tl + 4 * quad + r] = m;
                    }
            }
        } else if (i < 11) {
            // GEMM2: h1 = relu(.) -> ldsA (overwrites memB; A1 already in regs)
            const int col = 32 * (i - 3) + 16 * cw + ml;
            const float bias = b1_s[col];
            #pragma unroll
            for (int tl = 0; tl < 2; ++tl)
                #pragma unroll
                for (int r = 0; r < 4; ++r) {
                    const float v = fmaxf((tl ? acc1[r] : acc0[r]) + bias, 0.f);
                    const int ltok = 32 * tw + 16 * tl + 4 * quad + r;
                    ldsA[LA(ltok, col)] = f2bf(v);
                }
        } else {
            // GEMM3: h2 = relu(.); boxes = h2 @ w3 folded in-register
            const int col = 32 * (i - 11) + 16 * cw + ml;
            const float bias = b2_s[col];
            const float4 w3v = *(const float4*)&w3_s[col * 4];
            #pragma unroll
            for (int tl = 0; tl < 2; ++tl)
                #pragma unroll
                for (int r = 0; r < 4; ++r) {
                    const float v = fmaxf((tl ? acc1[r] : acc0[r]) + bias, 0.f);
                    psum[tl][r][0] = fmaf(v, w3v.x, psum[tl][r][0]);
                    psum[tl][r][1] = fmaf(v, w3v.y, psum[tl][r][1]);
                    psum[tl][r][2] = fmaf(v, w3v.z, psum[tl][r][2]);
                    psum[tl][r][3] = fmaf(v, w3v.w, psum[tl][r][3]);
                }
        }

        __syncthreads();                  // DMA(i+1) done; wbuf[cur] reads done; h1 visible
        cur ^= 1;
    }

    // ---- boxes: reduce psum over 16 col-lanes, cross-wave (cw) combine via LDS ----
    #pragma unroll
    for (int tl = 0; tl < 2; ++tl)
        #pragma unroll
        for (int r = 0; r < 4; ++r) {
            float4 pv;
            float* pva = (float*)&pv;
            #pragma unroll
            for (int c = 0; c < 4; ++c) {
                float v = psum[tl][r][c];
                v += __shfl_xor(v, 1);
                v += __shfl_xor(v, 2);
                v += __shfl_xor(v, 4);
                v += __shfl_xor(v, 8);
                pva[c] = v;
            }
            if (ml == 0)
                *(float4*)&boxp[cw][32 * tw + 16 * tl + 4 * quad + r][0] = pv;
        }
    __syncthreads();

    if (t < 64)
        ws_scores[gtok0 + t] = sigmoidf_(fmaxf(smax_s[0][t], smax_s[1][t]));
    {
        const int tok = t >> 2, c = t & 3;
        const float bx = boxp[0][tok][c] + boxp[1][tok][c] + b3[c];
        out_sboxes[(size_t)(gtok0 + tok) * 4 + c] = sigmoidf_(bx);
    }
}

// -------- Kernel 2: fp32 radix pre-select of top-KSEL candidates per batch --------
__global__ __launch_bounds__(256) void select_kernel(
    const float* __restrict__ scores,
    int* __restrict__ cand_idx, unsigned int* __restrict__ cand_cnt)
{
    const int bb = blockIdx.x;
    const int t = threadIdx.x;
    const int lane = t & 63;
    const float* s = scores + bb * NTOK;

    __shared__ unsigned int hist[256];
    __shared__ unsigned int prefix_s, rem_s, cnt_s;

    unsigned int prefix = 0, mask = 0;
    int remaining = KSEL;
    for (int pass = 0; pass < 4; pass++) {
        const int shift = 24 - 8 * pass;
        hist[t] = 0;
        __syncthreads();
        for (int n = t; n < NTOK; n += 256) {
            const unsigned int key = __float_as_uint(s[n]);
            const bool pred = ((key & mask) == prefix);
            const unsigned int bin = pred ? ((key >> shift) & 255u) : 0xFFFFu;
            const unsigned long long alive = __ballot(pred);
            if (alive) {
                const int leader = __builtin_ctzll(alive);
                const unsigned int lbin = (unsigned int)__shfl((int)bin, leader);
                const unsigned long long match = __ballot(pred && bin == lbin);
                if (lane == leader)
                    atomicAdd(&hist[lbin], (unsigned int)__popcll(match));
                else if (pred && bin != lbin)
                    atomicAdd(&hist[bin], 1u);
            }
        }
        __syncthreads();
        if (t == 0) {
            int rem = remaining; unsigned int bsel = 0;
            for (int bin = 255; bin >= 0; bin--) {
                int c = (int)hist[bin];
                if (c >= rem) { bsel = (unsigned int)bin; break; }
                rem -= c;
            }
            prefix_s = prefix | (bsel << shift);
            rem_s = (unsigned int)rem;
        }
        __syncthreads();
        prefix = prefix_s; remaining = (int)rem_s;
        mask |= 0xFFu << shift;
        __syncthreads();
    }
    const unsigned int Tkey = prefix;

    if (t == 0) cnt_s = 0;
    __syncthreads();
    for (int n = t; n < NTOK; n += 256) {
        const unsigned int key = __float_as_uint(s[n]);
        const bool pred = (key >= Tkey);
        const unsigned long long m = __ballot(pred);
        if (m) {
            const int leader = __builtin_ctzll(m);
            unsigned int base = 0;
            if (lane == leader) base = atomicAdd(&cnt_s, (unsigned int)__popcll(m));
            base = (unsigned int)__shfl((int)base, leader);
            if (pred) {
                const unsigned int pos =
                    base + (unsigned int)__popcll(m & ((1ull << lane) - 1ull));
                if (pos < CANDMAX) cand_idx[bb * CANDMAX + pos] = n;
            }
        }
    }
    __syncthreads();
    if (t == 0) {
        unsigned int c = cnt_s; if (c > CANDMAX) c = CANDMAX;
        cand_cnt[bb] = c;
    }
}

// -------- Kernel 3: f64 exact rescore, one block per candidate --------
__global__ __launch_bounds__(256) void rescore_kernel(
    const float* __restrict__ s3, const float* __restrict__ s4, const float* __restrict__ s5,
    const float* __restrict__ w_score, const float* __restrict__ b_score,
    const int* __restrict__ cand_idx, const unsigned int* __restrict__ cand_cnt,
    double* __restrict__ cand_score, float* __restrict__ cand_mem, int use_cmem)
{
    __shared__ float m_s[CDIM];
    __shared__ double part[256];

    const int t = threadIdx.x;
    const int bb = blockIdx.x / CANDMAX;
    const int cpos = blockIdx.x % CANDMAX;
    if ((unsigned int)cpos >= cand_cnt[bb]) return;

    const int n = cand_idx[bb * CANDMAX + cpos];
    const float* src; int nloc, lsz;
    locate_level(n, bb, s3, s4, s5, src, nloc, lsz);
    m_s[t] = src[(size_t)t * lsz + nloc];
    __syncthreads();

    if (use_cmem)
        cand_mem[((size_t)bb * CANDMAX + cpos) * CDIM + t] = m_s[t];

    const int ks = t >> 7;
    const int c = t & 127;
    double acc = 0.0;
    if (c < NCLS) {
        if (ks == 0) acc = (double)b_score[c];
        const int k0 = 128 * ks;
        for (int k = k0; k < k0 + 128; ++k)
            acc += (double)m_s[k] * (double)w_score[k * NCLS + c];
    }
    part[t] = acc;
    __syncthreads();

    if (t < 128) {
        double tot = (t < NCLS) ? (part[t] + part[t + 128]) : -1.0e300;
        part[t] = tot;
    }
    __syncthreads();

    if (t < 64) {
        double v = fmax(part[t], part[t + 64]);
        v = fmax(v, __shfl_xor(v, 1));
        v = fmax(v, __shfl_xor(v, 2));
        v = fmax(v, __shfl_xor(v, 4));
        v = fmax(v, __shfl_xor(v, 8));
        v = fmax(v, __shfl_xor(v, 16));
        v = fmax(v, __shfl_xor(v, 32));
        if (t == 0) cand_score[bb * CANDMAX + cpos] = v;
    }
}

// -------- Kernel 4: exact sort of candidates, emit top-300 (+cand position) --------
__global__ __launch_bounds__(512) void fsort_kernel(
    const double* __restrict__ cand_score, const int* __restrict__ cand_idx,
    const unsigned int* __restrict__ cand_cnt,
    float* __restrict__ out_idx_f, float* __restrict__ out_scores,
    int* __restrict__ ws_idx, int* __restrict__ ws_pos)
{
    __shared__ double ss[CANDMAX];
    __shared__ int    ii[CANDMAX];
    __shared__ int    pp[CANDMAX];
    const int bb = blockIdx.x;
    const int t = threadIdx.x;
    const unsigned int cnt = cand_cnt[bb];

    for (int i = t; i < CANDMAX; i += 512) {
        if ((unsigned int)i < cnt) {
            ss[i] = cand_score[bb * CANDMAX + i];
            ii[i] = cand_idx[bb * CANDMAX + i];
        } else {
            ss[i] = -1.0e300;
            ii[i] = 0x7FFFFFFF;
        }
        pp[i] = i;
    }
    __syncthreads();

    for (int ksz = 2; ksz <= CANDMAX; ksz <<= 1) {
        for (int j = ksz >> 1; j > 0; j >>= 1) {
            #pragma unroll
            for (int p = 0; p < CANDMAX / 512; p++) {
                const int i = p * 512 + t;
                const int ixj = i ^ j;
                if (ixj > i) {
                    double sa = ss[i], sb = ss[ixj];
                    int ia = ii[i], ib = ii[ixj];
                    const bool up = ((i & ksz) != 0);
                    const bool agtb = (sa > sb) || (sa == sb && ia < ib);
                    if (agtb == up) {
                        ss[i] = sb; ss[ixj] = sa;
                        ii[i] = ib; ii[ixj] = ia;
                        const int pa = pp[i]; pp[i] = pp[ixj]; pp[ixj] = pa;
                    }
                }
            }
            __syncthreads();
        }
    }

    for (int q = t; q < KQ; q += 512) {
        const double x = ss[q];
        const int idx = ii[q];
        out_scores[bb * KQ + q] = (float)(1.0 / (1.0 + exp(-x)));
        out_idx_f[bb * KQ + q] = (float)idx;
        ws_idx[bb * KQ + q] = idx;
        ws_pos[bb * KQ + q] = pp[q];
    }
}

// -------- Kernel 5: gather top-k memory rows, project, gather ref_points --------
__global__ __launch_bounds__(256) void gather_proj_kernel(
    const float* __restrict__ s3, const float* __restrict__ s4, const float* __restrict__ s5,
    const float* __restrict__ w_proj, const float* __restrict__ b_proj,
    const int* __restrict__ ws_idx, const int* __restrict__ ws_pos,
    const float* __restrict__ cand_mem, int use_cmem,
    const float* __restrict__ out_sboxes,
    float* __restrict__ out_tgt, float* __restrict__ out_ref)
{
    __shared__ float memQ[20][CDIM];
    __shared__ int qidx[20];
    __shared__ int qpos[20];
    const int t = threadIdx.x;
    const int bb = blockIdx.x / 15;
    const int tile = blockIdx.x % 15;
    const int q0 = tile * 20;

    if (t < 20) {
        qidx[t] = ws_idx[bb * KQ + q0 + t];
        qpos[t] = ws_pos[bb * KQ + q0 + t];
    }
    __syncthreads();

    if (use_cmem) {
        #pragma unroll 4
        for (int q = 0; q < 20; q++)
            memQ[q][t] = cand_mem[((size_t)bb * CANDMAX + qpos[q]) * CDIM + t];
    } else {
        #pragma unroll 4
        for (int q = 0; q < 20; q++) {
            const int n = qidx[q];
            const float* src; int nloc, lsz;
            locate_level(n, bb, s3, s4, s5, src, nloc, lsz);
            memQ[q][t] = src[(size_t)t * lsz + nloc];
        }
    }
    __syncthreads();

    const int j = t;
    float acc[20];
    #pragma unroll
    for (int q = 0; q < 20; q++) acc[q] = b_proj[j];
    for (int k = 0; k < CDIM; k++) {
        const float w = w_proj[(size_t)k * CDIM + j];
        #pragma unroll
        for (int q = 0; q < 20; q++) acc[q] = fmaf(memQ[q][k], w, acc[q]);
    }
    #pragma unroll
    for (int q = 0; q < 20; q++)
        out_tgt[(size_t)(bb * KQ + q0 + q) * CDIM + j] = acc[q];

    if (t < 80) {
        const int q = t >> 2, c = t & 3;
        const int n = qidx[q];
        out_ref[(size_t)(bb * KQ + q0 + q) * 4 + c] =
            out_sboxes[(size_t)(bb * NTOK + n) * 4 + c];
    }
}

extern "C" void kernel_launch(void* const* d_in, const int* in_sizes, int n_in,
                              void* d_out, int out_size, void* d_ws, size_t ws_size,
                              hipStream_t stream) {
    const float* s3      = (const float*)d_in[0];
    const float* s4      = (const float*)d_in[1];
    const float* s5      = (const float*)d_in[2];
    const float* w_score = (const float*)d_in[3];
    const float* b_score = (const float*)d_in[4];
    const float* w1      = (const float*)d_in[5];
    const float* b1      = (const float*)d_in[6];
    const float* w2      = (const float*)d_in[7];
    const float* b2      = (const float*)d_in[8];
    const float* w3      = (const float*)d_in[9];
    const float* b3      = (const float*)d_in[10];
    const float* w_proj  = (const float*)d_in[11];
    const float* b_proj  = (const float*)d_in[12];

    float* out = (float*)d_out;
    float* out_tgt    = out;                 // 16*300*256
    float* out_ref    = out + 1228800;       // 16*300*4
    float* out_logits = out + 1248000;       // 16*21504*80
    float* out_sboxes = out + 28773120;      // 16*21504*4
    float* out_idx    = out + 30149376;      // 16*300 (as float)
    float* out_scores = out + 30154176;      // 16*300

    char* ws = (char*)d_ws;
    float*        ws_scores  = (float*)(ws + 0);              // 1,376,256
    double*       cand_score = (double*)(ws + 1376256);       //   131,072
    int*          cand_idx   = (int*)(ws + 1507328);          //    65,536
    unsigned int* cand_cnt   = (unsigned int*)(ws + 1572864); //       256
    int*          ws_idx     = (int*)(ws + 1573120);          //    19,456
    int*          ws_pos     = (int*)(ws + 1592576);          //    19,456
    ushort_t*     w1T        = (ushort_t*)(ws + 1612032);     //   131,072
    ushort_t*     w2T        = (ushort_t*)(ws + 1743104);     //   131,072
    ushort_t*     wsT        = (ushort_t*)(ws + 1874176);     //    49,152
    float*        cand_mem   = (float*)(ws + 1923328);        // 16,777,216
    const int use_cmem = (ws_size >= (size_t)1923328 + 16777216) ? 1 : 0;

    prep_weights<<<608, 256, 0, stream>>>(w1, w2, w_score, w1T, w2T, wsT);

    enc_mfma_kernel<<<BATCH * 336, 256, 0, stream>>>(
        s3, s4, s5, w1T, w2T, wsT, b_score, b1, b2, w3, b3,
        out_logits, out_sboxes, ws_scores);

    select_kernel<<<BATCH, 256, 0, stream>>>(ws_scores, cand_idx, cand_cnt);

    rescore_kernel<<<BATCH * CANDMAX, 256, 0, stream>>>(
        s3, s4, s5, w_score, b_score, cand_idx, cand_cnt,
        cand_score, cand_mem, use_cmem);

    fsort_kernel<<<BATCH, 512, 0, stream>>>(
        cand_score, cand_idx, cand_cnt, out_idx, out_scores, ws_idx, ws_pos);

    gather_proj_kernel<<<BATCH * 15, 256, 0, stream>>>(
        s3, s4, s5, w_proj, b_proj, ws_idx, ws_pos, cand_mem, use_cmem,
        out_sboxes, out_tgt, out_ref);
}